// Round 15
// baseline (233.073 us; speedup 1.0000x reference)
//
#include <hip/hip_runtime.h>
#include <hip/hip_bf16.h>
#include <stdint.h>
#include <math.h>

// Problem dims (fixed)
#define NB  4
#define NS  2048
#define ND  768
#define NHD 12
#define NDK 64
#define NBH (NB*NHD)   // 48

// Q pre-scale: 1/sqrt(DK) * log2(e) so passes use raw exp2
#define QSCALE 0.180336879f

typedef short short8 __attribute__((ext_vector_type(8)));
typedef float f32x4  __attribute__((ext_vector_type(4)));
typedef float f32x16 __attribute__((ext_vector_type(16)));
typedef unsigned int uint2v __attribute__((ext_vector_type(2)));

#define MFMA16(a,b,c) __builtin_amdgcn_mfma_f32_16x16x32_bf16(a,b,c,0,0,0)
#define MFMA32(a,b,c) __builtin_amdgcn_mfma_f32_32x32x16_bf16(a,b,c,0,0,0)

// OCML native exp2: inlines to a single v_exp_f32 as a REAL VALU MachineInstr,
// so the compiler's MFMA->VALU hazard recognizer protects it. (Round-8
// inline-asm v_exp_f32 bypassed the hazard recognizer -> absmax 9.8e-2. BANNED.
// Round-6 manual ping-pong prefetch also banned pending disasm.)
extern "C" __device__ float __ocml_native_exp2_f32(float);
__device__ __forceinline__ float nexp2(float x){ return __ocml_native_exp2_f32(x); }

__device__ __forceinline__ short f2b(float f){
  union { float f; uint32_t u; } v; v.f = f;
  uint32_t u = v.u + 0x7fffu + ((v.u >> 16) & 1u);  // RNE
  return (short)(u >> 16);
}
__device__ __forceinline__ float b2f(short s){
  union { float f; uint32_t u; } v; v.u = ((uint32_t)(unsigned short)s) << 16; return v.f;
}
__device__ __forceinline__ uint32_t cvtpk(float lo, float hi){
  uint32_t r;
  asm("v_cvt_pk_bf16_f32 %0, %1, %2" : "=v"(r) : "v"(lo), "v"(hi));
  return r;
}
__device__ __forceinline__ short8 mk8(uint32_t a, uint32_t b, uint32_t c, uint32_t d){
  union { uint32_t u[4]; short8 v; } x;
  x.u[0]=a; x.u[1]=b; x.u[2]=c; x.u[3]=d; return x.v;
}
// P[16 f32] -> two bf16x8 PV A-fragments (verified round-5 layout).
__device__ __forceinline__ void pack2(const float* p, short8& o0, short8& o1){
  uint32_t x0 = cvtpk(p[0], p[1]),  x1 = cvtpk(p[2], p[3]);
  uint32_t y0 = cvtpk(p[4], p[5]),  y1 = cvtpk(p[6], p[7]);
  uint2v r02 = __builtin_amdgcn_permlane32_swap(x0, y0, false, false);
  uint2v r13 = __builtin_amdgcn_permlane32_swap(x1, y1, false, false);
  o0 = mk8(r02.x, r13.x, r02.y, r13.y);
  uint32_t x2 = cvtpk(p[8],  p[9]),  x3 = cvtpk(p[10], p[11]);
  uint32_t y2 = cvtpk(p[12], p[13]), y3 = cvtpk(p[14], p[15]);
  uint2v r46 = __builtin_amdgcn_permlane32_swap(x2, y2, false, false);
  uint2v r57 = __builtin_amdgcn_permlane32_swap(x3, y3, false, false);
  o1 = mk8(r46.x, r57.x, r46.y, r57.y);
}

__device__ __forceinline__ void gload16(const void* g, void* lds){
  __builtin_amdgcn_global_load_lds(
      (const __attribute__((address_space(1))) uint32_t*)g,
      (__attribute__((address_space(3))) uint32_t*)lds, 16, 0, 0);
}

// GEMM A/B fragment-granule layout (round 15): element (row m, col base c0,
// c0 8-aligned) of a row-major [R][768] bf16 matrix lives at
//   granule g = ((m>>7)*12 + c0/64)*16 + ((m>>4)&7)*2 + ((c0>>5)&1)
//   lane l = ((c0>>3)&3)*16 + (m&15),  8 elems
// so the GEMM's af/bf fragment load is granule_base + l: 64 lanes x 16B
// contiguous (the pass_c pattern, 846 TF). Bijective: (m,c0) <-> (g,l).
__device__ __forceinline__ size_t packed_idx(int m, int c0){
  int g = (((m >> 7)*12 + (c0 >> 6))*16) + (((m >> 4) & 7)*2) + ((c0 >> 5) & 1);
  return (size_t)g*512 + (size_t)((((c0 >> 3) & 3)*16) + (m & 15))*8;
}

// ---------------- fused fp32 -> bf16 cast of all 5 inputs ----------------
// X and Wq/Wk/Wv are written FRAGMENT-PACKED (consumed by the LDS-free
// gemm_qkv); W0 stays row-major (consumed by gemm_out's LDS core).
__global__ __launch_bounds__(256) void cast_all(const float* __restrict__ x,
    const float* __restrict__ wq, const float* __restrict__ wk,
    const float* __restrict__ wv, const float* __restrict__ w0,
    short* __restrict__ xf, short* __restrict__ wqf, short* __restrict__ wkf,
    short* __restrict__ wvf, short* __restrict__ w0b){
  const int NX = NB*NS*ND/8;   // 786432 granules of 8
  const int NW = ND*ND/8;      // 73728
  int i = blockIdx.x*256 + threadIdx.x;
  const float* src; short* dst; int off; bool packed;
  if (i < NX){ src = x; dst = xf; off = i; packed = true; }
  else {
    int j = i - NX; int wsel = j / NW; off = j - wsel*NW;
    src = (wsel==0)?wq:((wsel==1)?wk:((wsel==2)?wv:w0));
    dst = (wsel==0)?wqf:((wsel==1)?wkf:((wsel==2)?wvf:w0b));
    packed = (wsel != 3);
  }
  const f32x4* p = (const f32x4*)(src + (size_t)off*8);
  f32x4 v0 = p[0], v1 = p[1];
  short8 r;
  r[0]=f2b(v0[0]); r[1]=f2b(v0[1]); r[2]=f2b(v0[2]); r[3]=f2b(v0[3]);
  r[4]=f2b(v1[0]); r[5]=f2b(v1[1]); r[6]=f2b(v1[2]); r[7]=f2b(v1[3]);
  size_t didx;
  if (packed){
    int m  = off / 96;          // row (768 elems = 96 chunks per row)
    int c0 = (off % 96) * 8;    // col base
    didx = packed_idx(m, c0);
  } else {
    didx = (size_t)off * 8;
  }
  *(short8*)(dst + didx) = r;
}

// ------ 128x128x(K=768) bf16 GEMM core, BK=64 DOUBLE-BUFFERED (gemm_out) ------
// (round-14 core, kept for gemm_out which reads row-major Hd/W0b.)
__device__ __forceinline__ void gemm128_core(const short* __restrict__ A,
                                             const short* __restrict__ Bw,
                                             int rowA0, int rowB0,
                                             short* As, short* Bs, f32x4 acc[4][4]){
  const int t = threadIdx.x;
  const int l  = t & 63;
  const int wm = ((t >> 7) & 1) * 64;
  const int wn = ((t >> 6) & 1) * 64;
  const int lr = l & 15, lg = l >> 4;
  #pragma unroll
  for (int mt=0; mt<4; ++mt)
    #pragma unroll
    for (int nt=0; nt<4; ++nt) acc[mt][nt] = (f32x4){0.f,0.f,0.f,0.f};

  // prologue: stage tile 0 into buffer 0
  #pragma unroll
  for (int c = 0; c < 4; ++c){
    int u  = c*256 + t;
    int m  = u >> 3;
    int kb = ((u & 7) << 4) ^ ((m & 7) << 4);   // inverse-swizzled source
    gload16((const char*)(A  + (size_t)(rowA0 + m)*768) + kb,
            (char*)As + ((c*256 + (t & 0xC0)) << 4));
    gload16((const char*)(Bw + (size_t)(rowB0 + m)*768) + kb,
            (char*)Bs + ((c*256 + (t & 0xC0)) << 4));
  }
  __syncthreads();   // drains vmcnt(0): tile 0 resident

  for (int kt = 0; kt < 12; ++kt){
    const int cur = (kt & 1) * (128*64);
    const int nxt = ((kt + 1) & 1) * (128*64);
    if (kt < 11){
      #pragma unroll
      for (int c = 0; c < 4; ++c){
        int u  = c*256 + t;
        int m  = u >> 3;
        int kb = ((u & 7) << 4) ^ ((m & 7) << 4);
        gload16((const char*)(A  + (size_t)(rowA0 + m)*768 + (kt+1)*64) + kb,
                (char*)(As + nxt) + ((c*256 + (t & 0xC0)) << 4));
        gload16((const char*)(Bw + (size_t)(rowB0 + m)*768 + (kt+1)*64) + kb,
                (char*)(Bs + nxt) + ((c*256 + (t & 0xC0)) << 4));
      }
    }
    short8 af[4][2], bf[4][2];
    #pragma unroll
    for (int mt=0; mt<4; ++mt)
      #pragma unroll
      for (int ks=0; ks<2; ++ks){
        int m  = wm + mt*16 + lr;
        int kb = (ks*32 + lg*8) * 2;
        af[mt][ks] = *(const short8*)((const char*)(As + cur) + ((m*128 + kb) ^ ((m & 7) << 4)));
        int n  = wn + mt*16 + lr;
        bf[mt][ks] = *(const short8*)((const char*)(Bs + cur) + ((n*128 + kb) ^ ((n & 7) << 4)));
      }
    #pragma unroll
    for (int mt=0; mt<4; ++mt)
      #pragma unroll
      for (int nt=0; nt<4; ++nt){
        acc[mt][nt] = MFMA16(af[mt][0], bf[nt][0], acc[mt][nt]);
        acc[mt][nt] = MFMA16(af[mt][1], bf[nt][1], acc[mt][nt]);
      }
    __syncthreads();   // one barrier/tile: drains stage(t+1) + orders buffers
  }
}

// QKV fused: grid (64, 18). LDS-FREE (round 15): operands are fragment-packed
// granules (Xf, Wqf/Wkf/Wvf) loaded straight from global — the pass_c pattern.
// No barriers -> no vmcnt(0) drain (rounds 13/14 showed the __syncthreads
// drain, not buffering, was the m97-structure stall). MFMA order identical to
// the LDS core -> absmax must stay 2.441e-3. Q/K epilogue fragment-packed,
// Q pre-scaled by QSCALE; V row-major for pack_v (all unchanged).
__global__ __launch_bounds__(256) void gemm_qkv(const short* __restrict__ Xf,
    const short* __restrict__ Wqf, const short* __restrict__ Wkf, const short* __restrict__ Wvf,
    short* __restrict__ Qf, short* __restrict__ Kf, short* __restrict__ V){
  const int wsel = blockIdx.y / 6;
  const int nb   = (blockIdx.y % 6) * 128;
  const int rtw  = blockIdx.y % 6;
  const int xt   = blockIdx.x;
  const short8* Ag = (const short8*)Xf;
  const short8* Bg = (const short8*)((wsel==0) ? Wqf : ((wsel==1) ? Wkf : Wvf));
  const int t = threadIdx.x, l = t & 63;
  const int wm4 = ((t>>7)&1)*4, wn4 = ((t>>6)&1)*4;

  f32x4 acc[4][4];
  #pragma unroll
  for (int mt=0; mt<4; ++mt)
    #pragma unroll
    for (int nt=0; nt<4; ++nt) acc[mt][nt] = (f32x4){0.f,0.f,0.f,0.f};

  for (int kt = 0; kt < 12; ++kt){
    short8 af[4][2], bf[4][2];
    const int ga = (xt*12 + kt)*16;
    const int gb = (rtw*12 + kt)*16;
    #pragma unroll
    for (int mt=0; mt<4; ++mt)
      #pragma unroll
      for (int ks=0; ks<2; ++ks){
        af[mt][ks] = Ag[(size_t)(ga + (wm4+mt)*2 + ks)*64 + l];
        bf[mt][ks] = Bg[(size_t)(gb + (wn4+mt)*2 + ks)*64 + l];
      }
    #pragma unroll
    for (int mt=0; mt<4; ++mt)
      #pragma unroll
      for (int nt=0; nt<4; ++nt){
        acc[mt][nt] = MFMA16(af[mt][0], bf[nt][0], acc[mt][nt]);
        acc[mt][nt] = MFMA16(af[mt][1], bf[nt][1], acc[mt][nt]);
      }
  }

  const int wm = wm4*16, wn = wn4*16;
  const int lr = l & 15, lg = l >> 4;
  if (wsel == 2){
    #pragma unroll
    for (int mt=0; mt<4; ++mt)
      #pragma unroll
      for (int nt=0; nt<4; ++nt)
        #pragma unroll
        for (int r=0; r<4; ++r){
          int m = xt*128 + wm + mt*16 + lg*4 + r;
          int n = nb + wn + nt*16 + lr;
          V[(size_t)m*768 + n] = f2b(acc[mt][nt][r]);
        }
  } else {
    short* O = (wsel==0) ? Qf : Kf;
    const float scl = (wsel==0) ? QSCALE : 1.0f;
    const int bh = (xt >> 4)*NHD + ((nb + wn) >> 6);
    const int s0 = (xt & 15)*128 + wm;
    short* Ob = O + (size_t)bh*131072;   // 64 kt * 2048
    #pragma unroll
    for (int mt=0; mt<4; ++mt)
      #pragma unroll
      for (int nt=0; nt<4; ++nt)
        #pragma unroll
        for (int r=0; r<4; ++r){
          int s  = s0 + mt*16 + lg*4 + r;
          int dk = nt*16 + lr;
          Ob[(size_t)((s>>5)*4 + (dk>>4))*512 + ((dk>>3)&1)*256 + (s&31)*8 + (dk&7)]
            = f2b(acc[mt][nt][r] * scl);
        }
  }
}

// Final projection: grid (64, 6), round-14 dbuf LDS core (Hd/W0b row-major).
__global__ __launch_bounds__(256) void gemm_out(const short* __restrict__ Hb,
    const short* __restrict__ W0b, float* __restrict__ out){
  __shared__ __align__(16) short As[2*128*64];
  __shared__ __align__(16) short Bs[2*128*64];
  const int nb = blockIdx.y * 128;
  f32x4 acc[4][4];
  gemm128_core(Hb, W0b, blockIdx.x*128, nb, As, Bs, acc);
  const int t = threadIdx.x, l = t & 63;
  const int wm = ((t>>7)&1)*64, wn = ((t>>6)&1)*64;
  const int lr = l & 15, lg = l >> 4;
  #pragma unroll
  for (int mt=0; mt<4; ++mt)
    #pragma unroll
    for (int nt=0; nt<4; ++nt)
      #pragma unroll
      for (int r=0; r<4; ++r){
        int m = blockIdx.x*128 + wm + mt*16 + lg*4 + r;
        int n = nb + wn + nt*16 + lr;
        out[(size_t)m*768 + n] = acc[mt][nt][r];
      }
}

// Pass A: colsum over the QUERY axis. grid (32,48): block = one PAIR of 32-kv
// tiles of one bh (shared Q granule stream serves both); wave w covers q-tiles
// [w*16, w*16+16). XCD-swizzled (bijective, 1536%8==0).
// SEQUENTIAL A/B chains (round-10 interleave doubled live transients and
// dropped occupancy to ~2 waves/SIMD — neutral). min-waves=3 pins the budget.
__global__ __launch_bounds__(256, 3) void pass_a(const short* __restrict__ Qf,
                                                 const short* __restrict__ Kf,
                                                 float* __restrict__ invs){
  __shared__ float redA[2][4][32];
  const int t = threadIdx.x, w = t >> 6, l = t & 63;
  const int lq = l & 31, hf = l >> 5;
  const int linear = blockIdx.y * 32 + blockIdx.x;   // 1536 blocks
  const int c8 = linear & 7, j = linear >> 3;        // 192 per XCD group
  const int bh = c8 * 6 + (j >> 5);
  const int kp = j & 31;                              // kv-pair index

  const short8* KgA = (const short8*)(Kf + ((size_t)bh*64 + kp*2    )*2048);
  const short8* KgB = (const short8*)(Kf + ((size_t)bh*64 + kp*2 + 1)*2048);
  short8 kfA[4], kfB[4];
  #pragma unroll
  for (int c=0; c<4; ++c){ kfA[c] = KgA[c*64 + l]; kfB[c] = KgB[c*64 + l]; }

  float psA[16], psB[16];
  #pragma unroll
  for (int r=0; r<16; ++r){ psA[r] = 0.f; psB[r] = 0.f; }

  const short8* Qb = (const short8*)(Qf + (size_t)bh*131072);
  for (int qt = w*16; qt < w*16 + 16; ++qt){
    const short8* Qg = Qb + qt*256;
    short8 q0 = Qg[l], q1 = Qg[64+l], q2 = Qg[128+l], q3 = Qg[192+l];
    {
      f32x16 cA = {};
      cA = MFMA32(kfA[0], q0, cA);
      cA = MFMA32(kfA[1], q1, cA);
      cA = MFMA32(kfA[2], q2, cA);
      cA = MFMA32(kfA[3], q3, cA);
      #pragma unroll
      for (int r=0; r<16; ++r) psA[r] += nexp2(cA[r]);
    }
    {
      f32x16 cB = {};
      cB = MFMA32(kfB[0], q0, cB);
      cB = MFMA32(kfB[1], q1, cB);
      cB = MFMA32(kfB[2], q2, cB);
      cB = MFMA32(kfB[3], q3, cB);
      #pragma unroll
      for (int r=0; r<16; ++r) psB[r] += nexp2(cB[r]);
    }
  }
  #pragma unroll
  for (int r=0; r<16; ++r){
    float a = psA[r], b = psB[r];
    a += __shfl_xor(a, 1); a += __shfl_xor(a, 2);
    a += __shfl_xor(a, 4); a += __shfl_xor(a, 8); a += __shfl_xor(a, 16);
    b += __shfl_xor(b, 1); b += __shfl_xor(b, 2);
    b += __shfl_xor(b, 4); b += __shfl_xor(b, 8); b += __shfl_xor(b, 16);
    if (lq == 0){
      int kr = (r&3) + 8*(r>>2) + 4*hf;
      redA[0][w][kr] = a;
      redA[1][w][kr] = b;
    }
  }
  __syncthreads();
  if (t < 64){
    int kvt = t >> 5, kr = t & 31;
    float s = redA[kvt][0][kr] + redA[kvt][1][kr] + redA[kvt][2][kr] + redA[kvt][3][kr];
    invs[(size_t)bh*NS + (kp*2 + kvt)*32 + kr] = 1.0f / s;
  }
}

// V (b,s,h,dk) -> Vf fragment-packed with inverse colsum folded in.
__global__ __launch_bounds__(256) void pack_v(const short* __restrict__ V,
                                              const float* __restrict__ invs,
                                              short* __restrict__ Vf){
  __shared__ short tile[64][66];
  const int sb = blockIdx.x * 64;
  const int bh = blockIdx.y;
  const int b = bh / NHD, h = bh % NHD;
  const int t = threadIdx.x;
  {
    int r = t >> 2, dkb = (t & 3) * 16;
    float iv = invs[(size_t)bh*NS + sb + r];
    const short* src = V + ((size_t)(b*NS + sb + r)*NHD + h)*NDK + dkb;
    short8 v0 = *(const short8*)src;
    short8 v1 = *(const short8*)(src + 8);
    #pragma unroll
    for (int j=0;j<8;++j) tile[r][dkb+j]   = f2b(b2f(v0[j]) * iv);
    #pragma unroll
    for (int j=0;j<8;++j) tile[r][dkb+8+j] = f2b(b2f(v1[j]) * iv);
  }
  __syncthreads();
  {
    const int c = t >> 6, l = t & 63;
    const int lq = l & 31, hf = l >> 5;
    const int dk = (c>>1)*32 + lq;
    #pragma unroll
    for (int kt_l = 0; kt_l < 2; ++kt_l){
      int kv0 = kt_l*32 + (c&1)*16 + hf*8;
      short8 o;
      #pragma unroll
      for (int j=0;j<8;++j) o[j] = tile[kv0+j][dk];
      *(short8*)(Vf + (((size_t)bh*64 + (sb>>5) + kt_l)*256 + c*64 + l)*8) = o;
    }
  }
}

// pass_c cross-wave O-reduction + store for one q-tile (round-5-verified tail).
__device__ __forceinline__ void reduce_store(float (&red)[2][32][64],
                                             f32x16& a0, f32x16& a1,
                                             int w, int l, int lq, int hf,
                                             short* __restrict__ Hd,
                                             size_t bhNS, int qt){
  if (w >= 2){
    #pragma unroll
    for (int r=0; r<16; ++r){ red[w-2][r][l] = a0[r]; red[w-2][16+r][l] = a1[r]; }
  }
  __syncthreads();
  if (w < 2){
    #pragma unroll
    for (int r=0; r<16; ++r){ a0[r] += red[w][r][l]; a1[r] += red[w][16+r][l]; }
  }
  __syncthreads();
  if (w == 1){
    #pragma unroll
    for (int r=0; r<16; ++r){ red[0][r][l] = a0[r]; red[0][16+r][l] = a1[r]; }
  }
  __syncthreads();
  if (w == 0){
    #pragma unroll
    for (int r=0; r<16; ++r){
      a0[r] += red[0][r][l];
      a1[r] += red[0][16+r][l];
      int q = qt*32 + (r&3) + 8*(r>>2) + 4*hf;
      short* dst = Hd + (bhNS + q)*NDK;
      dst[lq]      = f2b(a0[r]);
      dst[32 + lq] = f2b(a1[r]);
    }
  }
}

// Pass C: grid (32,48): block = one PAIR of 32-q tiles of one bh; wave w covers
// kv-tiles [w*16, w*16+16) for BOTH q-tiles — K/V granules loaded once serve
// two QK/PV chains run SEQUENTIALLY (A fully, then B) so the c/p transient
// register set is reused between chains (round-10 interleave kept both live:
// ~2 waves/SIMD, neutral; round-11 sequential: confirmed win). min-waves=3.
// Partial O combined via 16KB LDS tree, run twice. XCD-swizzled.
__global__ __launch_bounds__(256, 3) void pass_c(const short* __restrict__ Qf,
                                                 const short* __restrict__ Kf,
                                                 const short* __restrict__ Vf,
                                                 short* __restrict__ Hd){
  __shared__ float red[2][32][64];   // 16 KB, reused sequentially for A and B
  const int t = threadIdx.x, w = t >> 6, l = t & 63;
  const int lq = l & 31, hf = l >> 5;
  const int linear = blockIdx.y * 32 + blockIdx.x;   // 1536 blocks
  const int c8 = linear & 7, j = linear >> 3;
  const int bh = c8 * 6 + (j >> 5);
  const int qp = j & 31;                              // q-pair index

  const short8* QgA = (const short8*)(Qf + ((size_t)bh*64 + qp*2    )*2048);
  const short8* QgB = (const short8*)(Qf + ((size_t)bh*64 + qp*2 + 1)*2048);
  short8 qfA[4], qfB[4];
  #pragma unroll
  for (int c=0; c<4; ++c){ qfA[c] = QgA[c*64 + l]; qfB[c] = QgB[c*64 + l]; }

  const short8* Kb = (const short8*)(Kf + (size_t)bh*131072);
  const short8* Vb = (const short8*)(Vf + (size_t)bh*131072);

  f32x16 accA0 = {}, accA1 = {}, accB0 = {}, accB1 = {};

  for (int kt = w*16; kt < w*16 + 16; ++kt){
    const short8* Kg = Kb + kt*256;
    const short8* Vg = Vb + kt*256;
    short8 k0 = Kg[l], k1 = Kg[64+l], k2 = Kg[128+l], k3 = Kg[192+l];
    short8 v0 = Vg[l], v1 = Vg[64+l], v2 = Vg[128+l], v3 = Vg[192+l];

    {  // chain A
      f32x16 cA = {};
      cA = MFMA32(k0, qfA[0], cA);
      cA = MFMA32(k1, qfA[1], cA);
      cA = MFMA32(k2, qfA[2], cA);
      cA = MFMA32(k3, qfA[3], cA);
      float pA[16];
      #pragma unroll
      for (int r=0; r<16; ++r) pA[r] = nexp2(cA[r]);
      short8 paA0, paA1;
      pack2(pA, paA0, paA1);
      accA0 = MFMA32(paA0, v0, accA0);
      accA0 = MFMA32(paA1, v1, accA0);
      accA1 = MFMA32(paA0, v2, accA1);
      accA1 = MFMA32(paA1, v3, accA1);
    }
    {  // chain B (reuses A's transient registers)
      f32x16 cB = {};
      cB = MFMA32(k0, qfB[0], cB);
      cB = MFMA32(k1, qfB[1], cB);
      cB = MFMA32(k2, qfB[2], cB);
      cB = MFMA32(k3, qfB[3], cB);
      float pB[16];
      #pragma unroll
      for (int r=0; r<16; ++r) pB[r] = nexp2(cB[r]);
      short8 paB0, paB1;
      pack2(pB, paB0, paB1);
      accB0 = MFMA32(paB0, v0, accB0);
      accB0 = MFMA32(paB1, v1, accB0);
      accB1 = MFMA32(paB0, v2, accB1);
      accB1 = MFMA32(paB1, v3, accB1);
    }
  }

  const size_t bhNS = (size_t)bh*NS;
  reduce_store(red, accA0, accA1, w, l, lq, hf, Hd, bhNS, qp*2);
  __syncthreads();
  reduce_store(red, accB0, accB1, w, l, lq, hf, Hd, bhNS, qp*2 + 1);
}

extern "C" void kernel_launch(void* const* d_in, const int* in_sizes, int n_in,
                              void* d_out, int out_size, void* d_ws, size_t ws_size,
                              hipStream_t stream){
  (void)in_sizes; (void)n_in; (void)out_size; (void)ws_size;
  const float* x  = (const float*)d_in[0];
  const float* Wq = (const float*)d_in[1];
  const float* Wk = (const float*)d_in[2];
  const float* Wv = (const float*)d_in[3];
  const float* W0 = (const float*)d_in[4];

  char* ws = (char*)d_ws;
  const size_t SZ_X = (size_t)NB*NS*ND*2;   // 12,582,912 B
  const size_t SZ_W = (size_t)ND*ND*2;      //  1,179,648 B
  short* Xf   = (short*)(ws);               // fragment-packed X; reused as Hd after gemm_qkv
  short* Wqf  = (short*)(ws + SZ_X);
  short* Wkf  = (short*)(ws + SZ_X + 1*SZ_W);
  short* Wvf  = (short*)(ws + SZ_X + 2*SZ_W);
  short* W0b  = (short*)(ws + SZ_X + 3*SZ_W);
  short* Qf   = (short*)(ws + 1*SZ_X + 4*SZ_W);
  short* Kf   = (short*)(ws + 2*SZ_X + 4*SZ_W);
  short* V    = (short*)(ws + 3*SZ_X + 4*SZ_W);
  short* Vf   = (short*)(ws + 4*SZ_X + 4*SZ_W);
  float* invs = (float*)(ws + 5*SZ_X + 4*SZ_W);
  short* Hd   = Xf;                          // Xf dead after gemm_qkv
  float* out  = (float*)d_out;

  // 786432 + 4*73728 = 1,081,344 granules / 256 = 4224 blocks (exact)
  cast_all<<<dim3(4224), dim3(256), 0, stream>>>(x, Wq, Wk, Wv, W0,
                                                 Xf, Wqf, Wkf, Wvf, W0b);

  gemm_qkv<<<dim3(64,18), dim3(256), 0, stream>>>(Xf, Wqf, Wkf, Wvf, Qf, Kf, V);
  pass_a<<<dim3(32,48), dim3(256), 0, stream>>>(Qf, Kf, invs);
  pack_v<<<dim3(32,48), dim3(256), 0, stream>>>(V, invs, Vf);
  pass_c<<<dim3(32,48), dim3(256), 0, stream>>>(Qf, Kf, Vf, Hd);
  gemm_out<<<dim3(64,6), dim3(256), 0, stream>>>(Hd, W0b, out);
}

// Round 16
// 162.985 us; speedup vs baseline: 1.4300x; 1.4300x over previous
//
#include <hip/hip_runtime.h>
#include <hip/hip_bf16.h>
#include <stdint.h>
#include <math.h>

// Problem dims (fixed)
#define NB  4
#define NS  2048
#define ND  768
#define NHD 12
#define NDK 64
#define NBH (NB*NHD)   // 48

// Q pre-scale: 1/sqrt(DK) * log2(e) so passes use raw exp2
#define QSCALE 0.180336879f

typedef short short8 __attribute__((ext_vector_type(8)));
typedef float f32x4  __attribute__((ext_vector_type(4)));
typedef float f32x16 __attribute__((ext_vector_type(16)));
typedef unsigned int uint2v __attribute__((ext_vector_type(2)));

#define MFMA16(a,b,c) __builtin_amdgcn_mfma_f32_16x16x32_bf16(a,b,c,0,0,0)
#define MFMA32(a,b,c) __builtin_amdgcn_mfma_f32_32x32x16_bf16(a,b,c,0,0,0)

// OCML native exp2: inlines to a single v_exp_f32 as a REAL VALU MachineInstr,
// so the compiler's MFMA->VALU hazard recognizer protects it. (Round-8
// inline-asm v_exp_f32 bypassed the hazard recognizer -> absmax 9.8e-2. BANNED.
// Round-6 manual ping-pong prefetch also banned pending disasm.
// Round-15 lesson: LDS-free fragment-streaming GEMM is BANNED for gemm_qkv —
// LDS provides bandwidth amplification (1 L2 crossing per tile byte); removing
// it cost 1.8x. Only pays at >=64 FLOP/byte (pass_c), not 32 (128^2 GEMM).)
extern "C" __device__ float __ocml_native_exp2_f32(float);
__device__ __forceinline__ float nexp2(float x){ return __ocml_native_exp2_f32(x); }

__device__ __forceinline__ short f2b(float f){
  union { float f; uint32_t u; } v; v.f = f;
  uint32_t u = v.u + 0x7fffu + ((v.u >> 16) & 1u);  // RNE
  return (short)(u >> 16);
}
__device__ __forceinline__ float b2f(short s){
  union { float f; uint32_t u; } v; v.u = ((uint32_t)(unsigned short)s) << 16; return v.f;
}
__device__ __forceinline__ uint32_t cvtpk(float lo, float hi){
  uint32_t r;
  asm("v_cvt_pk_bf16_f32 %0, %1, %2" : "=v"(r) : "v"(lo), "v"(hi));
  return r;
}
__device__ __forceinline__ short8 mk8(uint32_t a, uint32_t b, uint32_t c, uint32_t d){
  union { uint32_t u[4]; short8 v; } x;
  x.u[0]=a; x.u[1]=b; x.u[2]=c; x.u[3]=d; return x.v;
}
// P[16 f32] -> two bf16x8 PV A-fragments (verified round-5 layout).
__device__ __forceinline__ void pack2(const float* p, short8& o0, short8& o1){
  uint32_t x0 = cvtpk(p[0], p[1]),  x1 = cvtpk(p[2], p[3]);
  uint32_t y0 = cvtpk(p[4], p[5]),  y1 = cvtpk(p[6], p[7]);
  uint2v r02 = __builtin_amdgcn_permlane32_swap(x0, y0, false, false);
  uint2v r13 = __builtin_amdgcn_permlane32_swap(x1, y1, false, false);
  o0 = mk8(r02.x, r13.x, r02.y, r13.y);
  uint32_t x2 = cvtpk(p[8],  p[9]),  x3 = cvtpk(p[10], p[11]);
  uint32_t y2 = cvtpk(p[12], p[13]), y3 = cvtpk(p[14], p[15]);
  uint2v r46 = __builtin_amdgcn_permlane32_swap(x2, y2, false, false);
  uint2v r57 = __builtin_amdgcn_permlane32_swap(x3, y3, false, false);
  o1 = mk8(r46.x, r57.x, r46.y, r57.y);
}

__device__ __forceinline__ void gload16(const void* g, void* lds){
  __builtin_amdgcn_global_load_lds(
      (const __attribute__((address_space(1))) uint32_t*)g,
      (__attribute__((address_space(3))) uint32_t*)lds, 16, 0, 0);
}

// ---------------- fused fp32 -> bf16 cast of all 5 inputs ----------------
__global__ __launch_bounds__(256) void cast_all(const float* __restrict__ x,
    const float* __restrict__ wq, const float* __restrict__ wk,
    const float* __restrict__ wv, const float* __restrict__ w0,
    short* __restrict__ xb, short* __restrict__ wqb, short* __restrict__ wkb,
    short* __restrict__ wvb, short* __restrict__ w0b){
  const int NX = NB*NS*ND/8;   // 786432 granules of 8
  const int NW = ND*ND/8;      // 73728
  int i = blockIdx.x*256 + threadIdx.x;
  const float* src; short* dst; int off;
  if (i < NX){ src = x; dst = xb; off = i; }
  else {
    int j = i - NX; int wsel = j / NW; off = j - wsel*NW;
    src = (wsel==0)?wq:((wsel==1)?wk:((wsel==2)?wv:w0));
    dst = (wsel==0)?wqb:((wsel==1)?wkb:((wsel==2)?wvb:w0b));
  }
  const f32x4* p = (const f32x4*)(src + (size_t)off*8);
  f32x4 v0 = p[0], v1 = p[1];
  short8 r;
  r[0]=f2b(v0[0]); r[1]=f2b(v0[1]); r[2]=f2b(v0[2]); r[3]=f2b(v0[3]);
  r[4]=f2b(v1[0]); r[5]=f2b(v1[1]); r[6]=f2b(v1[2]); r[7]=f2b(v1[3]);
  *(short8*)(dst + (size_t)off*8) = r;
}

// ------ 128x128x(K=768) bf16 GEMM core, BK=64 DOUBLE-BUFFERED (round 14) ------
// Round-14-verified core (60.7us gemm_qkv). Round-15 LDS-free variant REVERTED
// (109us — LDS bandwidth amplification is essential at this arithmetic
// intensity; see banned-list note at top).
__device__ __forceinline__ void gemm128_core(const short* __restrict__ A,
                                             const short* __restrict__ Bw,
                                             int rowA0, int rowB0,
                                             short* As, short* Bs, f32x4 acc[4][4]){
  const int t = threadIdx.x;
  const int l  = t & 63;
  const int wm = ((t >> 7) & 1) * 64;
  const int wn = ((t >> 6) & 1) * 64;
  const int lr = l & 15, lg = l >> 4;
  #pragma unroll
  for (int mt=0; mt<4; ++mt)
    #pragma unroll
    for (int nt=0; nt<4; ++nt) acc[mt][nt] = (f32x4){0.f,0.f,0.f,0.f};

  // prologue: stage tile 0 into buffer 0
  #pragma unroll
  for (int c = 0; c < 4; ++c){
    int u  = c*256 + t;
    int m  = u >> 3;
    int kb = ((u & 7) << 4) ^ ((m & 7) << 4);   // inverse-swizzled source
    gload16((const char*)(A  + (size_t)(rowA0 + m)*768) + kb,
            (char*)As + ((c*256 + (t & 0xC0)) << 4));
    gload16((const char*)(Bw + (size_t)(rowB0 + m)*768) + kb,
            (char*)Bs + ((c*256 + (t & 0xC0)) << 4));
  }
  __syncthreads();   // drains vmcnt(0): tile 0 resident

  for (int kt = 0; kt < 12; ++kt){
    const int cur = (kt & 1) * (128*64);
    const int nxt = ((kt + 1) & 1) * (128*64);
    if (kt < 11){
      #pragma unroll
      for (int c = 0; c < 4; ++c){
        int u  = c*256 + t;
        int m  = u >> 3;
        int kb = ((u & 7) << 4) ^ ((m & 7) << 4);
        gload16((const char*)(A  + (size_t)(rowA0 + m)*768 + (kt+1)*64) + kb,
                (char*)(As + nxt) + ((c*256 + (t & 0xC0)) << 4));
        gload16((const char*)(Bw + (size_t)(rowB0 + m)*768 + (kt+1)*64) + kb,
                (char*)(Bs + nxt) + ((c*256 + (t & 0xC0)) << 4));
      }
    }
    short8 af[4][2], bf[4][2];
    #pragma unroll
    for (int mt=0; mt<4; ++mt)
      #pragma unroll
      for (int ks=0; ks<2; ++ks){
        int m  = wm + mt*16 + lr;
        int kb = (ks*32 + lg*8) * 2;
        af[mt][ks] = *(const short8*)((const char*)(As + cur) + ((m*128 + kb) ^ ((m & 7) << 4)));
        int n  = wn + mt*16 + lr;
        bf[mt][ks] = *(const short8*)((const char*)(Bs + cur) + ((n*128 + kb) ^ ((n & 7) << 4)));
      }
    #pragma unroll
    for (int mt=0; mt<4; ++mt)
      #pragma unroll
      for (int nt=0; nt<4; ++nt){
        acc[mt][nt] = MFMA16(af[mt][0], bf[nt][0], acc[mt][nt]);
        acc[mt][nt] = MFMA16(af[mt][1], bf[nt][1], acc[mt][nt]);
      }
    __syncthreads();   // one barrier/tile: drains stage(t+1) + orders buffers
  }
}

// QKV fused: grid (64, 18), DEFAULT block mapping. Q/K written fragment-
// packed, Q pre-scaled by QSCALE; V row-major for pack_v. (Round-14 exact.)
__global__ __launch_bounds__(256) void gemm_qkv(const short* __restrict__ Xb,
    const short* __restrict__ Wqb, const short* __restrict__ Wkb, const short* __restrict__ Wvb,
    short* __restrict__ Qf, short* __restrict__ Kf, short* __restrict__ V){
  __shared__ __align__(16) short As[2*128*64];   // 32 KB (double-buffered)
  __shared__ __align__(16) short Bs[2*128*64];   // 32 KB
  const int wsel = blockIdx.y / 6;
  const int nb   = (blockIdx.y % 6) * 128;
  const short* W = (wsel==0) ? Wqb : ((wsel==1) ? Wkb : Wvb);
  f32x4 acc[4][4];
  gemm128_core(Xb, W, blockIdx.x*128, nb, As, Bs, acc);
  const int t = threadIdx.x, l = t & 63;
  const int wm = ((t>>7)&1)*64, wn = ((t>>6)&1)*64;
  const int lr = l & 15, lg = l >> 4;
  if (wsel == 2){
    #pragma unroll
    for (int mt=0; mt<4; ++mt)
      #pragma unroll
      for (int nt=0; nt<4; ++nt)
        #pragma unroll
        for (int r=0; r<4; ++r){
          int m = blockIdx.x*128 + wm + mt*16 + lg*4 + r;
          int n = nb + wn + nt*16 + lr;
          V[(size_t)m*768 + n] = f2b(acc[mt][nt][r]);
        }
  } else {
    short* O = (wsel==0) ? Qf : Kf;
    const float scl = (wsel==0) ? QSCALE : 1.0f;
    const int bh = (blockIdx.x >> 4)*NHD + ((nb + wn) >> 6);
    const int s0 = (blockIdx.x & 15)*128 + wm;
    short* Ob = O + (size_t)bh*131072;   // 64 kt * 2048
    #pragma unroll
    for (int mt=0; mt<4; ++mt)
      #pragma unroll
      for (int nt=0; nt<4; ++nt)
        #pragma unroll
        for (int r=0; r<4; ++r){
          int s  = s0 + mt*16 + lg*4 + r;
          int dk = nt*16 + lr;
          Ob[(size_t)((s>>5)*4 + (dk>>4))*512 + ((dk>>3)&1)*256 + (s&31)*8 + (dk&7)]
            = f2b(acc[mt][nt][r] * scl);
        }
  }
}

// Final projection: grid (64, 6), default mapping. fp32 output.
__global__ __launch_bounds__(256) void gemm_out(const short* __restrict__ Hb,
    const short* __restrict__ W0b, float* __restrict__ out){
  __shared__ __align__(16) short As[2*128*64];
  __shared__ __align__(16) short Bs[2*128*64];
  const int nb = blockIdx.y * 128;
  f32x4 acc[4][4];
  gemm128_core(Hb, W0b, blockIdx.x*128, nb, As, Bs, acc);
  const int t = threadIdx.x, l = t & 63;
  const int wm = ((t>>7)&1)*64, wn = ((t>>6)&1)*64;
  const int lr = l & 15, lg = l >> 4;
  #pragma unroll
  for (int mt=0; mt<4; ++mt)
    #pragma unroll
    for (int nt=0; nt<4; ++nt)
      #pragma unroll
      for (int r=0; r<4; ++r){
        int m = blockIdx.x*128 + wm + mt*16 + lg*4 + r;
        int n = nb + wn + nt*16 + lr;
        out[(size_t)m*768 + n] = acc[mt][nt][r];
      }
}

// Pass A: colsum over the QUERY axis. grid (32,48): block = one PAIR of 32-kv
// tiles of one bh (shared Q granule stream serves both); wave w covers q-tiles
// [w*16, w*16+16). XCD-swizzled (bijective, 1536%8==0). SEQUENTIAL A/B chains.
// min-waves=3 pins the budget. ROUND-16: T5 s_setprio(1) around MFMA clusters
// (barrier-free main loop -> waves at different phases; m191 regime).
__global__ __launch_bounds__(256, 3) void pass_a(const short* __restrict__ Qf,
                                                 const short* __restrict__ Kf,
                                                 float* __restrict__ invs){
  __shared__ float redA[2][4][32];
  const int t = threadIdx.x, w = t >> 6, l = t & 63;
  const int lq = l & 31, hf = l >> 5;
  const int linear = blockIdx.y * 32 + blockIdx.x;   // 1536 blocks
  const int c8 = linear & 7, j = linear >> 3;        // 192 per XCD group
  const int bh = c8 * 6 + (j >> 5);
  const int kp = j & 31;                              // kv-pair index

  const short8* KgA = (const short8*)(Kf + ((size_t)bh*64 + kp*2    )*2048);
  const short8* KgB = (const short8*)(Kf + ((size_t)bh*64 + kp*2 + 1)*2048);
  short8 kfA[4], kfB[4];
  #pragma unroll
  for (int c=0; c<4; ++c){ kfA[c] = KgA[c*64 + l]; kfB[c] = KgB[c*64 + l]; }

  float psA[16], psB[16];
  #pragma unroll
  for (int r=0; r<16; ++r){ psA[r] = 0.f; psB[r] = 0.f; }

  const short8* Qb = (const short8*)(Qf + (size_t)bh*131072);
  for (int qt = w*16; qt < w*16 + 16; ++qt){
    const short8* Qg = Qb + qt*256;
    short8 q0 = Qg[l], q1 = Qg[64+l], q2 = Qg[128+l], q3 = Qg[192+l];
    {
      f32x16 cA = {};
      __builtin_amdgcn_s_setprio(1);
      cA = MFMA32(kfA[0], q0, cA);
      cA = MFMA32(kfA[1], q1, cA);
      cA = MFMA32(kfA[2], q2, cA);
      cA = MFMA32(kfA[3], q3, cA);
      __builtin_amdgcn_s_setprio(0);
      #pragma unroll
      for (int r=0; r<16; ++r) psA[r] += nexp2(cA[r]);
    }
    {
      f32x16 cB = {};
      __builtin_amdgcn_s_setprio(1);
      cB = MFMA32(kfB[0], q0, cB);
      cB = MFMA32(kfB[1], q1, cB);
      cB = MFMA32(kfB[2], q2, cB);
      cB = MFMA32(kfB[3], q3, cB);
      __builtin_amdgcn_s_setprio(0);
      #pragma unroll
      for (int r=0; r<16; ++r) psB[r] += nexp2(cB[r]);
    }
  }
  #pragma unroll
  for (int r=0; r<16; ++r){
    float a = psA[r], b = psB[r];
    a += __shfl_xor(a, 1); a += __shfl_xor(a, 2);
    a += __shfl_xor(a, 4); a += __shfl_xor(a, 8); a += __shfl_xor(a, 16);
    b += __shfl_xor(b, 1); b += __shfl_xor(b, 2);
    b += __shfl_xor(b, 4); b += __shfl_xor(b, 8); b += __shfl_xor(b, 16);
    if (lq == 0){
      int kr = (r&3) + 8*(r>>2) + 4*hf;
      redA[0][w][kr] = a;
      redA[1][w][kr] = b;
    }
  }
  __syncthreads();
  if (t < 64){
    int kvt = t >> 5, kr = t & 31;
    float s = redA[kvt][0][kr] + redA[kvt][1][kr] + redA[kvt][2][kr] + redA[kvt][3][kr];
    invs[(size_t)bh*NS + (kp*2 + kvt)*32 + kr] = 1.0f / s;
  }
}

// V (b,s,h,dk) -> Vf fragment-packed with inverse colsum folded in.
__global__ __launch_bounds__(256) void pack_v(const short* __restrict__ V,
                                              const float* __restrict__ invs,
                                              short* __restrict__ Vf){
  __shared__ short tile[64][66];
  const int sb = blockIdx.x * 64;
  const int bh = blockIdx.y;
  const int b = bh / NHD, h = bh % NHD;
  const int t = threadIdx.x;
  {
    int r = t >> 2, dkb = (t & 3) * 16;
    float iv = invs[(size_t)bh*NS + sb + r];
    const short* src = V + ((size_t)(b*NS + sb + r)*NHD + h)*NDK + dkb;
    short8 v0 = *(const short8*)src;
    short8 v1 = *(const short8*)(src + 8);
    #pragma unroll
    for (int j=0;j<8;++j) tile[r][dkb+j]   = f2b(b2f(v0[j]) * iv);
    #pragma unroll
    for (int j=0;j<8;++j) tile[r][dkb+8+j] = f2b(b2f(v1[j]) * iv);
  }
  __syncthreads();
  {
    const int c = t >> 6, l = t & 63;
    const int lq = l & 31, hf = l >> 5;
    const int dk = (c>>1)*32 + lq;
    #pragma unroll
    for (int kt_l = 0; kt_l < 2; ++kt_l){
      int kv0 = kt_l*32 + (c&1)*16 + hf*8;
      short8 o;
      #pragma unroll
      for (int j=0;j<8;++j) o[j] = tile[kv0+j][dk];
      *(short8*)(Vf + (((size_t)bh*64 + (sb>>5) + kt_l)*256 + c*64 + l)*8) = o;
    }
  }
}

// pass_c cross-wave O-reduction + store for one q-tile (round-5-verified tail).
__device__ __forceinline__ void reduce_store(float (&red)[2][32][64],
                                             f32x16& a0, f32x16& a1,
                                             int w, int l, int lq, int hf,
                                             short* __restrict__ Hd,
                                             size_t bhNS, int qt){
  if (w >= 2){
    #pragma unroll
    for (int r=0; r<16; ++r){ red[w-2][r][l] = a0[r]; red[w-2][16+r][l] = a1[r]; }
  }
  __syncthreads();
  if (w < 2){
    #pragma unroll
    for (int r=0; r<16; ++r){ a0[r] += red[w][r][l]; a1[r] += red[w][16+r][l]; }
  }
  __syncthreads();
  if (w == 1){
    #pragma unroll
    for (int r=0; r<16; ++r){ red[0][r][l] = a0[r]; red[0][16+r][l] = a1[r]; }
  }
  __syncthreads();
  if (w == 0){
    #pragma unroll
    for (int r=0; r<16; ++r){
      a0[r] += red[0][r][l];
      a1[r] += red[0][16+r][l];
      int q = qt*32 + (r&3) + 8*(r>>2) + 4*hf;
      short* dst = Hd + (bhNS + q)*NDK;
      dst[lq]      = f2b(a0[r]);
      dst[32 + lq] = f2b(a1[r]);
    }
  }
}

// Pass C: grid (32,48): block = one PAIR of 32-q tiles of one bh; wave w covers
// kv-tiles [w*16, w*16+16) for BOTH q-tiles — K/V granules loaded once serve
// two QK/PV chains run SEQUENTIALLY (round-11 verified). min-waves=3.
// Partial O combined via 16KB LDS tree, run twice. XCD-swizzled.
// ROUND-16: T5 s_setprio(1) around each MFMA cluster (QK and PV) — barrier-
// free main loop gives wave phase diversity (m191 regime, NOT m190's lockstep).
__global__ __launch_bounds__(256, 3) void pass_c(const short* __restrict__ Qf,
                                                 const short* __restrict__ Kf,
                                                 const short* __restrict__ Vf,
                                                 short* __restrict__ Hd){
  __shared__ float red[2][32][64];   // 16 KB, reused sequentially for A and B
  const int t = threadIdx.x, w = t >> 6, l = t & 63;
  const int lq = l & 31, hf = l >> 5;
  const int linear = blockIdx.y * 32 + blockIdx.x;   // 1536 blocks
  const int c8 = linear & 7, j = linear >> 3;
  const int bh = c8 * 6 + (j >> 5);
  const int qp = j & 31;                              // q-pair index

  const short8* QgA = (const short8*)(Qf + ((size_t)bh*64 + qp*2    )*2048);
  const short8* QgB = (const short8*)(Qf + ((size_t)bh*64 + qp*2 + 1)*2048);
  short8 qfA[4], qfB[4];
  #pragma unroll
  for (int c=0; c<4; ++c){ qfA[c] = QgA[c*64 + l]; qfB[c] = QgB[c*64 + l]; }

  const short8* Kb = (const short8*)(Kf + (size_t)bh*131072);
  const short8* Vb = (const short8*)(Vf + (size_t)bh*131072);

  f32x16 accA0 = {}, accA1 = {}, accB0 = {}, accB1 = {};

  for (int kt = w*16; kt < w*16 + 16; ++kt){
    const short8* Kg = Kb + kt*256;
    const short8* Vg = Vb + kt*256;
    short8 k0 = Kg[l], k1 = Kg[64+l], k2 = Kg[128+l], k3 = Kg[192+l];
    short8 v0 = Vg[l], v1 = Vg[64+l], v2 = Vg[128+l], v3 = Vg[192+l];

    {  // chain A
      f32x16 cA = {};
      __builtin_amdgcn_s_setprio(1);
      cA = MFMA32(k0, qfA[0], cA);
      cA = MFMA32(k1, qfA[1], cA);
      cA = MFMA32(k2, qfA[2], cA);
      cA = MFMA32(k3, qfA[3], cA);
      __builtin_amdgcn_s_setprio(0);
      float pA[16];
      #pragma unroll
      for (int r=0; r<16; ++r) pA[r] = nexp2(cA[r]);
      short8 paA0, paA1;
      pack2(pA, paA0, paA1);
      __builtin_amdgcn_s_setprio(1);
      accA0 = MFMA32(paA0, v0, accA0);
      accA0 = MFMA32(paA1, v1, accA0);
      accA1 = MFMA32(paA0, v2, accA1);
      accA1 = MFMA32(paA1, v3, accA1);
      __builtin_amdgcn_s_setprio(0);
    }
    {  // chain B (reuses A's transient registers)
      f32x16 cB = {};
      __builtin_amdgcn_s_setprio(1);
      cB = MFMA32(k0, qfB[0], cB);
      cB = MFMA32(k1, qfB[1], cB);
      cB = MFMA32(k2, qfB[2], cB);
      cB = MFMA32(k3, qfB[3], cB);
      __builtin_amdgcn_s_setprio(0);
      float pB[16];
      #pragma unroll
      for (int r=0; r<16; ++r) pB[r] = nexp2(cB[r]);
      short8 paB0, paB1;
      pack2(pB, paB0, paB1);
      __builtin_amdgcn_s_setprio(1);
      accB0 = MFMA32(paB0, v0, accB0);
      accB0 = MFMA32(paB1, v1, accB0);
      accB1 = MFMA32(paB0, v2, accB1);
      accB1 = MFMA32(paB1, v3, accB1);
      __builtin_amdgcn_s_setprio(0);
    }
  }

  const size_t bhNS = (size_t)bh*NS;
  reduce_store(red, accA0, accA1, w, l, lq, hf, Hd, bhNS, qp*2);
  __syncthreads();
  reduce_store(red, accB0, accB1, w, l, lq, hf, Hd, bhNS, qp*2 + 1);
}

extern "C" void kernel_launch(void* const* d_in, const int* in_sizes, int n_in,
                              void* d_out, int out_size, void* d_ws, size_t ws_size,
                              hipStream_t stream){
  (void)in_sizes; (void)n_in; (void)out_size; (void)ws_size;
  const float* x  = (const float*)d_in[0];
  const float* Wq = (const float*)d_in[1];
  const float* Wk = (const float*)d_in[2];
  const float* Wv = (const float*)d_in[3];
  const float* W0 = (const float*)d_in[4];

  char* ws = (char*)d_ws;
  const size_t SZ_X = (size_t)NB*NS*ND*2;   // 12,582,912 B
  const size_t SZ_W = (size_t)ND*ND*2;      //  1,179,648 B
  short* Xb   = (short*)(ws);               // reused as Hd after QKV GEMM
  short* Wqb  = (short*)(ws + SZ_X);
  short* Wkb  = (short*)(ws + SZ_X + 1*SZ_W);
  short* Wvb  = (short*)(ws + SZ_X + 2*SZ_W);
  short* W0b  = (short*)(ws + SZ_X + 3*SZ_W);
  short* Qf   = (short*)(ws + 1*SZ_X + 4*SZ_W);
  short* Kf   = (short*)(ws + 2*SZ_X + 4*SZ_W);
  short* V    = (short*)(ws + 3*SZ_X + 4*SZ_W);
  short* Vf   = (short*)(ws + 4*SZ_X + 4*SZ_W);
  float* invs = (float*)(ws + 5*SZ_X + 4*SZ_W);
  short* Hd   = Xb;
  float* out  = (float*)d_out;

  // 786432 + 4*73728 = 1,081,344 granules / 256 = 4224 blocks (exact)
  cast_all<<<dim3(4224), dim3(256), 0, stream>>>(x, Wq, Wk, Wv, W0,
                                                 Xb, Wqb, Wkb, Wvb, W0b);

  gemm_qkv<<<dim3(64,18), dim3(256), 0, stream>>>(Xb, Wqb, Wkb, Wvb, Qf, Kf, V);
  pass_a<<<dim3(32,48), dim3(256), 0, stream>>>(Qf, Kf, invs);
  pack_v<<<dim3(32,48), dim3(256), 0, stream>>>(V, invs, Vf);
  pass_c<<<dim3(32,48), dim3(256), 0, stream>>>(Qf, Kf, Vf, Hd);
  gemm_out<<<dim3(64,6), dim3(256), 0, stream>>>(Hd, W0b, out);
}

// Round 17
// 159.217 us; speedup vs baseline: 1.4639x; 1.0237x over previous
//
#include <hip/hip_runtime.h>
#include <hip/hip_bf16.h>
#include <stdint.h>
#include <math.h>

// Problem dims (fixed)
#define NB  4
#define NS  2048
#define ND  768
#define NHD 12
#define NDK 64
#define NBH (NB*NHD)   // 48

// Q pre-scale: 1/sqrt(DK) * log2(e) so passes use raw exp2
#define QSCALE 0.180336879f

typedef short short8 __attribute__((ext_vector_type(8)));
typedef float f32x4  __attribute__((ext_vector_type(4)));
typedef float f32x16 __attribute__((ext_vector_type(16)));
typedef unsigned int uint2v __attribute__((ext_vector_type(2)));

#define MFMA16(a,b,c) __builtin_amdgcn_mfma_f32_16x16x32_bf16(a,b,c,0,0,0)
#define MFMA32(a,b,c) __builtin_amdgcn_mfma_f32_32x32x16_bf16(a,b,c,0,0,0)

// OCML native exp2: inlines to a single v_exp_f32 as a REAL VALU MachineInstr,
// so the compiler's MFMA->VALU hazard recognizer protects it. (Round-8
// inline-asm v_exp_f32 bypassed the hazard recognizer -> absmax 9.8e-2. BANNED.
// Round-6 manual ping-pong prefetch also banned pending disasm.
// Round-15: LDS-free fragment-streaming GEMM BANNED for gemm_qkv — LDS is
// bandwidth amplification at 32 FLOP/byte; removing it cost 1.8x.)
extern "C" __device__ float __ocml_native_exp2_f32(float);
__device__ __forceinline__ float nexp2(float x){ return __ocml_native_exp2_f32(x); }

__device__ __forceinline__ short f2b(float f){
  union { float f; uint32_t u; } v; v.f = f;
  uint32_t u = v.u + 0x7fffu + ((v.u >> 16) & 1u);  // RNE
  return (short)(u >> 16);
}
__device__ __forceinline__ float b2f(short s){
  union { float f; uint32_t u; } v; v.u = ((uint32_t)(unsigned short)s) << 16; return v.f;
}
__device__ __forceinline__ uint32_t cvtpk(float lo, float hi){
  uint32_t r;
  asm("v_cvt_pk_bf16_f32 %0, %1, %2" : "=v"(r) : "v"(lo), "v"(hi));
  return r;
}
__device__ __forceinline__ short8 mk8(uint32_t a, uint32_t b, uint32_t c, uint32_t d){
  union { uint32_t u[4]; short8 v; } x;
  x.u[0]=a; x.u[1]=b; x.u[2]=c; x.u[3]=d; return x.v;
}
// P[16 f32] -> two bf16x8 PV A-fragments (verified round-5 layout).
__device__ __forceinline__ void pack2(const float* p, short8& o0, short8& o1){
  uint32_t x0 = cvtpk(p[0], p[1]),  x1 = cvtpk(p[2], p[3]);
  uint32_t y0 = cvtpk(p[4], p[5]),  y1 = cvtpk(p[6], p[7]);
  uint2v r02 = __builtin_amdgcn_permlane32_swap(x0, y0, false, false);
  uint2v r13 = __builtin_amdgcn_permlane32_swap(x1, y1, false, false);
  o0 = mk8(r02.x, r13.x, r02.y, r13.y);
  uint32_t x2 = cvtpk(p[8],  p[9]),  x3 = cvtpk(p[10], p[11]);
  uint32_t y2 = cvtpk(p[12], p[13]), y3 = cvtpk(p[14], p[15]);
  uint2v r46 = __builtin_amdgcn_permlane32_swap(x2, y2, false, false);
  uint2v r57 = __builtin_amdgcn_permlane32_swap(x3, y3, false, false);
  o1 = mk8(r46.x, r57.x, r46.y, r57.y);
}

__device__ __forceinline__ void gload16(const void* g, void* lds){
  __builtin_amdgcn_global_load_lds(
      (const __attribute__((address_space(1))) uint32_t*)g,
      (__attribute__((address_space(3))) uint32_t*)lds, 16, 0, 0);
}

// ---------------- fused fp32 -> bf16 cast of all 5 inputs ----------------
__global__ __launch_bounds__(256) void cast_all(const float* __restrict__ x,
    const float* __restrict__ wq, const float* __restrict__ wk,
    const float* __restrict__ wv, const float* __restrict__ w0,
    short* __restrict__ xb, short* __restrict__ wqb, short* __restrict__ wkb,
    short* __restrict__ wvb, short* __restrict__ w0b){
  const int NX = NB*NS*ND/8;   // 786432 granules of 8
  const int NW = ND*ND/8;      // 73728
  int i = blockIdx.x*256 + threadIdx.x;
  const float* src; short* dst; int off;
  if (i < NX){ src = x; dst = xb; off = i; }
  else {
    int j = i - NX; int wsel = j / NW; off = j - wsel*NW;
    src = (wsel==0)?wq:((wsel==1)?wk:((wsel==2)?wv:w0));
    dst = (wsel==0)?wqb:((wsel==1)?wkb:((wsel==2)?wvb:w0b));
  }
  const f32x4* p = (const f32x4*)(src + (size_t)off*8);
  f32x4 v0 = p[0], v1 = p[1];
  short8 r;
  r[0]=f2b(v0[0]); r[1]=f2b(v0[1]); r[2]=f2b(v0[2]); r[3]=f2b(v0[3]);
  r[4]=f2b(v1[0]); r[5]=f2b(v1[1]); r[6]=f2b(v1[2]); r[7]=f2b(v1[3]);
  *(short8*)(dst + (size_t)off*8) = r;
}

// ------ 128x128x(K=768) bf16 GEMM core, BK=64 DOUBLE-BUFFERED (round 14) ------
__device__ __forceinline__ void gemm128_core(const short* __restrict__ A,
                                             const short* __restrict__ Bw,
                                             int rowA0, int rowB0,
                                             short* As, short* Bs, f32x4 acc[4][4]){
  const int t = threadIdx.x;
  const int l  = t & 63;
  const int wm = ((t >> 7) & 1) * 64;
  const int wn = ((t >> 6) & 1) * 64;
  const int lr = l & 15, lg = l >> 4;
  #pragma unroll
  for (int mt=0; mt<4; ++mt)
    #pragma unroll
    for (int nt=0; nt<4; ++nt) acc[mt][nt] = (f32x4){0.f,0.f,0.f,0.f};

  // prologue: stage tile 0 into buffer 0
  #pragma unroll
  for (int c = 0; c < 4; ++c){
    int u  = c*256 + t;
    int m  = u >> 3;
    int kb = ((u & 7) << 4) ^ ((m & 7) << 4);   // inverse-swizzled source
    gload16((const char*)(A  + (size_t)(rowA0 + m)*768) + kb,
            (char*)As + ((c*256 + (t & 0xC0)) << 4));
    gload16((const char*)(Bw + (size_t)(rowB0 + m)*768) + kb,
            (char*)Bs + ((c*256 + (t & 0xC0)) << 4));
  }
  __syncthreads();   // drains vmcnt(0): tile 0 resident

  for (int kt = 0; kt < 12; ++kt){
    const int cur = (kt & 1) * (128*64);
    const int nxt = ((kt + 1) & 1) * (128*64);
    if (kt < 11){
      #pragma unroll
      for (int c = 0; c < 4; ++c){
        int u  = c*256 + t;
        int m  = u >> 3;
        int kb = ((u & 7) << 4) ^ ((m & 7) << 4);
        gload16((const char*)(A  + (size_t)(rowA0 + m)*768 + (kt+1)*64) + kb,
                (char*)(As + nxt) + ((c*256 + (t & 0xC0)) << 4));
        gload16((const char*)(Bw + (size_t)(rowB0 + m)*768 + (kt+1)*64) + kb,
                (char*)(Bs + nxt) + ((c*256 + (t & 0xC0)) << 4));
      }
    }
    short8 af[4][2], bf[4][2];
    #pragma unroll
    for (int mt=0; mt<4; ++mt)
      #pragma unroll
      for (int ks=0; ks<2; ++ks){
        int m  = wm + mt*16 + lr;
        int kb = (ks*32 + lg*8) * 2;
        af[mt][ks] = *(const short8*)((const char*)(As + cur) + ((m*128 + kb) ^ ((m & 7) << 4)));
        int n  = wn + mt*16 + lr;
        bf[mt][ks] = *(const short8*)((const char*)(Bs + cur) + ((n*128 + kb) ^ ((n & 7) << 4)));
      }
    #pragma unroll
    for (int mt=0; mt<4; ++mt)
      #pragma unroll
      for (int nt=0; nt<4; ++nt){
        acc[mt][nt] = MFMA16(af[mt][0], bf[nt][0], acc[mt][nt]);
        acc[mt][nt] = MFMA16(af[mt][1], bf[nt][1], acc[mt][nt]);
      }
    __syncthreads();   // one barrier/tile: drains stage(t+1) + orders buffers
  }
}

// QKV fused: grid (64, 18), DEFAULT block mapping. Q/K written fragment-
// packed, Q pre-scaled by QSCALE; V row-major for the fused pack-V tail in
// pass_a. (Round-14 exact.)
__global__ __launch_bounds__(256) void gemm_qkv(const short* __restrict__ Xb,
    const short* __restrict__ Wqb, const short* __restrict__ Wkb, const short* __restrict__ Wvb,
    short* __restrict__ Qf, short* __restrict__ Kf, short* __restrict__ V){
  __shared__ __align__(16) short As[2*128*64];   // 32 KB (double-buffered)
  __shared__ __align__(16) short Bs[2*128*64];   // 32 KB
  const int wsel = blockIdx.y / 6;
  const int nb   = (blockIdx.y % 6) * 128;
  const short* W = (wsel==0) ? Wqb : ((wsel==1) ? Wkb : Wvb);
  f32x4 acc[4][4];
  gemm128_core(Xb, W, blockIdx.x*128, nb, As, Bs, acc);
  const int t = threadIdx.x, l = t & 63;
  const int wm = ((t>>7)&1)*64, wn = ((t>>6)&1)*64;
  const int lr = l & 15, lg = l >> 4;
  if (wsel == 2){
    #pragma unroll
    for (int mt=0; mt<4; ++mt)
      #pragma unroll
      for (int nt=0; nt<4; ++nt)
        #pragma unroll
        for (int r=0; r<4; ++r){
          int m = blockIdx.x*128 + wm + mt*16 + lg*4 + r;
          int n = nb + wn + nt*16 + lr;
          V[(size_t)m*768 + n] = f2b(acc[mt][nt][r]);
        }
  } else {
    short* O = (wsel==0) ? Qf : Kf;
    const float scl = (wsel==0) ? QSCALE : 1.0f;
    const int bh = (blockIdx.x >> 4)*NHD + ((nb + wn) >> 6);
    const int s0 = (blockIdx.x & 15)*128 + wm;
    short* Ob = O + (size_t)bh*131072;   // 64 kt * 2048
    #pragma unroll
    for (int mt=0; mt<4; ++mt)
      #pragma unroll
      for (int nt=0; nt<4; ++nt)
        #pragma unroll
        for (int r=0; r<4; ++r){
          int s  = s0 + mt*16 + lg*4 + r;
          int dk = nt*16 + lr;
          Ob[(size_t)((s>>5)*4 + (dk>>4))*512 + ((dk>>3)&1)*256 + (s&31)*8 + (dk&7)]
            = f2b(acc[mt][nt][r] * scl);
        }
  }
}

// Final projection: grid (64, 6), default mapping. fp32 output.
__global__ __launch_bounds__(256) void gemm_out(const short* __restrict__ Hb,
    const short* __restrict__ W0b, float* __restrict__ out){
  __shared__ __align__(16) short As[2*128*64];
  __shared__ __align__(16) short Bs[2*128*64];
  const int nb = blockIdx.y * 128;
  f32x4 acc[4][4];
  gemm128_core(Hb, W0b, blockIdx.x*128, nb, As, Bs, acc);
  const int t = threadIdx.x, l = t & 63;
  const int wm = ((t>>7)&1)*64, wn = ((t>>6)&1)*64;
  const int lr = l & 15, lg = l >> 4;
  #pragma unroll
  for (int mt=0; mt<4; ++mt)
    #pragma unroll
    for (int nt=0; nt<4; ++nt)
      #pragma unroll
      for (int r=0; r<4; ++r){
        int m = blockIdx.x*128 + wm + mt*16 + lg*4 + r;
        int n = nb + wn + nt*16 + lr;
        out[(size_t)m*768 + n] = acc[mt][nt][r];
      }
}

// Pass A + fused pack-V (round 17): grid (32,48): block = one PAIR of 32-kv
// tiles (kv rows [kp*64, kp*64+64)) of one bh. Phase 1 (round-16-verified):
// colsum over the QUERY axis, sequential A/B chains, T5 setprio, shfl reduce
// into redA. Phase 2 (NEW): this block's colsums are FINAL for exactly the
// 64 kv rows the old pack_v block (sb=kp*64) consumed -> run pack_v's body
// here, reading inv=1/s from LDS. Deletes the pack_v kernel + launch gap and
// the entire invs global round-trip (pack_v was its only consumer).
// Index check: invL[r>>5][r&31] == old invs[bh*NS + kp*64 + r]; Vf granule
// (sb>>5)=kp*2 matches kv-tile ids kp*2, kp*2+1. Arithmetic bit-identical.
__global__ __launch_bounds__(256, 3) void pass_a(const short* __restrict__ Qf,
                                                 const short* __restrict__ Kf,
                                                 const short* __restrict__ V,
                                                 short* __restrict__ Vf){
  __shared__ float redA[2][4][32];
  __shared__ float invL[2][32];
  __shared__ short tile[64][66];
  const int t = threadIdx.x, w = t >> 6, l = t & 63;
  const int lq = l & 31, hf = l >> 5;
  const int linear = blockIdx.y * 32 + blockIdx.x;   // 1536 blocks
  const int c8 = linear & 7, j = linear >> 3;        // 192 per XCD group
  const int bh = c8 * 6 + (j >> 5);
  const int kp = j & 31;                              // kv-pair index

  const short8* KgA = (const short8*)(Kf + ((size_t)bh*64 + kp*2    )*2048);
  const short8* KgB = (const short8*)(Kf + ((size_t)bh*64 + kp*2 + 1)*2048);
  short8 kfA[4], kfB[4];
  #pragma unroll
  for (int c=0; c<4; ++c){ kfA[c] = KgA[c*64 + l]; kfB[c] = KgB[c*64 + l]; }

  float psA[16], psB[16];
  #pragma unroll
  for (int r=0; r<16; ++r){ psA[r] = 0.f; psB[r] = 0.f; }

  const short8* Qb = (const short8*)(Qf + (size_t)bh*131072);
  for (int qt = w*16; qt < w*16 + 16; ++qt){
    const short8* Qg = Qb + qt*256;
    short8 q0 = Qg[l], q1 = Qg[64+l], q2 = Qg[128+l], q3 = Qg[192+l];
    {
      f32x16 cA = {};
      __builtin_amdgcn_s_setprio(1);
      cA = MFMA32(kfA[0], q0, cA);
      cA = MFMA32(kfA[1], q1, cA);
      cA = MFMA32(kfA[2], q2, cA);
      cA = MFMA32(kfA[3], q3, cA);
      __builtin_amdgcn_s_setprio(0);
      #pragma unroll
      for (int r=0; r<16; ++r) psA[r] += nexp2(cA[r]);
    }
    {
      f32x16 cB = {};
      __builtin_amdgcn_s_setprio(1);
      cB = MFMA32(kfB[0], q0, cB);
      cB = MFMA32(kfB[1], q1, cB);
      cB = MFMA32(kfB[2], q2, cB);
      cB = MFMA32(kfB[3], q3, cB);
      __builtin_amdgcn_s_setprio(0);
      #pragma unroll
      for (int r=0; r<16; ++r) psB[r] += nexp2(cB[r]);
    }
  }
  #pragma unroll
  for (int r=0; r<16; ++r){
    float a = psA[r], b = psB[r];
    a += __shfl_xor(a, 1); a += __shfl_xor(a, 2);
    a += __shfl_xor(a, 4); a += __shfl_xor(a, 8); a += __shfl_xor(a, 16);
    b += __shfl_xor(b, 1); b += __shfl_xor(b, 2);
    b += __shfl_xor(b, 4); b += __shfl_xor(b, 8); b += __shfl_xor(b, 16);
    if (lq == 0){
      int kr = (r&3) + 8*(r>>2) + 4*hf;
      redA[0][w][kr] = a;
      redA[1][w][kr] = b;
    }
  }
  __syncthreads();
  if (t < 64){
    int kvt = t >> 5, kr = t & 31;
    float s = redA[kvt][0][kr] + redA[kvt][1][kr] + redA[kvt][2][kr] + redA[kvt][3][kr];
    invL[kvt][kr] = 1.0f / s;
  }
  __syncthreads();

  // ---- fused pack_v tail (verified pack_v body, sb = kp*64, inv from LDS) ----
  const int sb = kp * 64;
  const int b = bh / NHD, h = bh % NHD;
  {
    int r = t >> 2, dkb = (t & 3) * 16;
    float iv = invL[r >> 5][r & 31];
    const short* src = V + ((size_t)(b*NS + sb + r)*NHD + h)*NDK + dkb;
    short8 v0 = *(const short8*)src;
    short8 v1 = *(const short8*)(src + 8);
    #pragma unroll
    for (int jj=0;jj<8;++jj) tile[r][dkb+jj]   = f2b(b2f(v0[jj]) * iv);
    #pragma unroll
    for (int jj=0;jj<8;++jj) tile[r][dkb+8+jj] = f2b(b2f(v1[jj]) * iv);
  }
  __syncthreads();
  {
    const int c = t >> 6;
    const int dk = (c>>1)*32 + lq;
    #pragma unroll
    for (int kt_l = 0; kt_l < 2; ++kt_l){
      int kv0 = kt_l*32 + (c&1)*16 + hf*8;
      short8 o;
      #pragma unroll
      for (int jj=0;jj<8;++jj) o[jj] = tile[kv0+jj][dk];
      *(short8*)(Vf + (((size_t)bh*64 + kp*2 + kt_l)*256 + c*64 + l)*8) = o;
    }
  }
}

// pass_c cross-wave O-reduction + store for one q-tile (round-5-verified tail).
__device__ __forceinline__ void reduce_store(float (&red)[2][32][64],
                                             f32x16& a0, f32x16& a1,
                                             int w, int l, int lq, int hf,
                                             short* __restrict__ Hd,
                                             size_t bhNS, int qt){
  if (w >= 2){
    #pragma unroll
    for (int r=0; r<16; ++r){ red[w-2][r][l] = a0[r]; red[w-2][16+r][l] = a1[r]; }
  }
  __syncthreads();
  if (w < 2){
    #pragma unroll
    for (int r=0; r<16; ++r){ a0[r] += red[w][r][l]; a1[r] += red[w][16+r][l]; }
  }
  __syncthreads();
  if (w == 1){
    #pragma unroll
    for (int r=0; r<16; ++r){ red[0][r][l] = a0[r]; red[0][16+r][l] = a1[r]; }
  }
  __syncthreads();
  if (w == 0){
    #pragma unroll
    for (int r=0; r<16; ++r){
      a0[r] += red[0][r][l];
      a1[r] += red[0][16+r][l];
      int q = qt*32 + (r&3) + 8*(r>>2) + 4*hf;
      short* dst = Hd + (bhNS + q)*NDK;
      dst[lq]      = f2b(a0[r]);
      dst[32 + lq] = f2b(a1[r]);
    }
  }
}

// Pass C: grid (32,48): block = one PAIR of 32-q tiles of one bh; wave w covers
// kv-tiles [w*16, w*16+16) for BOTH q-tiles — K/V granules loaded once serve
// two QK/PV chains run SEQUENTIALLY (round-11 verified). min-waves=3.
// T5 setprio around MFMA clusters (round-16 verified, +4%). Partial O combined
// via 16KB LDS tree, run twice. XCD-swizzled.
__global__ __launch_bounds__(256, 3) void pass_c(const short* __restrict__ Qf,
                                                 const short* __restrict__ Kf,
                                                 const short* __restrict__ Vf,
                                                 short* __restrict__ Hd){
  __shared__ float red[2][32][64];   // 16 KB, reused sequentially for A and B
  const int t = threadIdx.x, w = t >> 6, l = t & 63;
  const int lq = l & 31, hf = l >> 5;
  const int linear = blockIdx.y * 32 + blockIdx.x;   // 1536 blocks
  const int c8 = linear & 7, j = linear >> 3;
  const int bh = c8 * 6 + (j >> 5);
  const int qp = j & 31;                              // q-pair index

  const short8* QgA = (const short8*)(Qf + ((size_t)bh*64 + qp*2    )*2048);
  const short8* QgB = (const short8*)(Qf + ((size_t)bh*64 + qp*2 + 1)*2048);
  short8 qfA[4], qfB[4];
  #pragma unroll
  for (int c=0; c<4; ++c){ qfA[c] = QgA[c*64 + l]; qfB[c] = QgB[c*64 + l]; }

  const short8* Kb = (const short8*)(Kf + (size_t)bh*131072);
  const short8* Vb = (const short8*)(Vf + (size_t)bh*131072);

  f32x16 accA0 = {}, accA1 = {}, accB0 = {}, accB1 = {};

  for (int kt = w*16; kt < w*16 + 16; ++kt){
    const short8* Kg = Kb + kt*256;
    const short8* Vg = Vb + kt*256;
    short8 k0 = Kg[l], k1 = Kg[64+l], k2 = Kg[128+l], k3 = Kg[192+l];
    short8 v0 = Vg[l], v1 = Vg[64+l], v2 = Vg[128+l], v3 = Vg[192+l];

    {  // chain A
      f32x16 cA = {};
      __builtin_amdgcn_s_setprio(1);
      cA = MFMA32(k0, qfA[0], cA);
      cA = MFMA32(k1, qfA[1], cA);
      cA = MFMA32(k2, qfA[2], cA);
      cA = MFMA32(k3, qfA[3], cA);
      __builtin_amdgcn_s_setprio(0);
      float pA[16];
      #pragma unroll
      for (int r=0; r<16; ++r) pA[r] = nexp2(cA[r]);
      short8 paA0, paA1;
      pack2(pA, paA0, paA1);
      __builtin_amdgcn_s_setprio(1);
      accA0 = MFMA32(paA0, v0, accA0);
      accA0 = MFMA32(paA1, v1, accA0);
      accA1 = MFMA32(paA0, v2, accA1);
      accA1 = MFMA32(paA1, v3, accA1);
      __builtin_amdgcn_s_setprio(0);
    }
    {  // chain B (reuses A's transient registers)
      f32x16 cB = {};
      __builtin_amdgcn_s_setprio(1);
      cB = MFMA32(k0, qfB[0], cB);
      cB = MFMA32(k1, qfB[1], cB);
      cB = MFMA32(k2, qfB[2], cB);
      cB = MFMA32(k3, qfB[3], cB);
      __builtin_amdgcn_s_setprio(0);
      float pB[16];
      #pragma unroll
      for (int r=0; r<16; ++r) pB[r] = nexp2(cB[r]);
      short8 paB0, paB1;
      pack2(pB, paB0, paB1);
      __builtin_amdgcn_s_setprio(1);
      accB0 = MFMA32(paB0, v0, accB0);
      accB0 = MFMA32(paB1, v1, accB0);
      accB1 = MFMA32(paB0, v2, accB1);
      accB1 = MFMA32(paB1, v3, accB1);
      __builtin_amdgcn_s_setprio(0);
    }
  }

  const size_t bhNS = (size_t)bh*NS;
  reduce_store(red, accA0, accA1, w, l, lq, hf, Hd, bhNS, qp*2);
  __syncthreads();
  reduce_store(red, accB0, accB1, w, l, lq, hf, Hd, bhNS, qp*2 + 1);
}

extern "C" void kernel_launch(void* const* d_in, const int* in_sizes, int n_in,
                              void* d_out, int out_size, void* d_ws, size_t ws_size,
                              hipStream_t stream){
  (void)in_sizes; (void)n_in; (void)out_size; (void)ws_size;
  const float* x  = (const float*)d_in[0];
  const float* Wq = (const float*)d_in[1];
  const float* Wk = (const float*)d_in[2];
  const float* Wv = (const float*)d_in[3];
  const float* W0 = (const float*)d_in[4];

  char* ws = (char*)d_ws;
  const size_t SZ_X = (size_t)NB*NS*ND*2;   // 12,582,912 B
  const size_t SZ_W = (size_t)ND*ND*2;      //  1,179,648 B
  short* Xb   = (short*)(ws);               // reused as Hd after QKV GEMM
  short* Wqb  = (short*)(ws + SZ_X);
  short* Wkb  = (short*)(ws + SZ_X + 1*SZ_W);
  short* Wvb  = (short*)(ws + SZ_X + 2*SZ_W);
  short* W0b  = (short*)(ws + SZ_X + 3*SZ_W);
  short* Qf   = (short*)(ws + 1*SZ_X + 4*SZ_W);
  short* Kf   = (short*)(ws + 2*SZ_X + 4*SZ_W);
  short* V    = (short*)(ws + 3*SZ_X + 4*SZ_W);
  short* Vf   = (short*)(ws + 4*SZ_X + 4*SZ_W);
  short* Hd   = Xb;
  float* out  = (float*)d_out;

  // 786432 + 4*73728 = 1,081,344 granules / 256 = 4224 blocks (exact)
  cast_all<<<dim3(4224), dim3(256), 0, stream>>>(x, Wq, Wk, Wv, W0,
                                                 Xb, Wqb, Wkb, Wvb, W0b);

  gemm_qkv<<<dim3(64,18), dim3(256), 0, stream>>>(Xb, Wqb, Wkb, Wvb, Qf, Kf, V);
  pass_a<<<dim3(32,48), dim3(256), 0, stream>>>(Qf, Kf, V, Vf);
  pass_c<<<dim3(32,48), dim3(256), 0, stream>>>(Qf, Kf, Vf, Hd);
  gemm_out<<<dim3(64,6), dim3(256), 0, stream>>>(Hd, W0b, out);
}